// Round 5
// baseline (1048.529 us; speedup 1.0000x reference)
//
#include <hip/hip_runtime.h>

#define HID 50
#define FOURH 200
#define TSTEPS 2048
#define NBATCH 1024

#define LOG2E 1.44269504f

typedef _Float16 v2h __attribute__((ext_vector_type(2)));

__device__ __forceinline__ float frcp(float x)  { return __builtin_amdgcn_rcpf(x); }
__device__ __forceinline__ float fexp2(float x) { return __builtin_amdgcn_exp2f(x); }
__device__ __forceinline__ v2h bc_v2h(unsigned int u) {
    return __builtin_bit_cast(v2h, u);
}

// 2 waves per batch (2048 waves = 2/SIMD, fills the ~4cy single-wave issue
// cadence gap). Gate split: wave0 owns {i,f}, wave1 owns {g,o} -> 50 fdot2
// per wave instead of 101. h broadcast via LDS packed-half2 (7 uniform
// ds_read_b128, no repack); partner wave hides the LDS latency. Activated
// gate values exchanged via stride-1 LDS; both waves then compute c,h
// redundantly (bit-identical: ig*gg = actA*pA on both waves). Sigmoid sign
// and tanh's 2x folded into per-wave weight scales, so every activation is
// s = rcp(1+exp2(z)); act = fma(mA,s,aA).
// (Round 4 note: resubmission — Round 4 bench died to MI355X container infra
// failure with no diagnostic; Round 1 had the same signature and the
// unchanged resubmission then passed. Kernel audited: barriers uniform, no
// cross-iteration exch race, no graph-capture-illegal host calls.)
__global__ __launch_bounds__(128, 1)
void lstm_2wave_kernel(const float* __restrict__ x,
                       const float* __restrict__ Wx,
                       const float* __restrict__ Wh,
                       const float* __restrict__ bias,
                       const float* __restrict__ Wd,
                       const float* __restrict__ bd,
                       float* __restrict__ out) {
    const int b    = blockIdx.x;
    const int tid  = threadIdx.x;
    const int wv   = tid >> 6;          // 0 or 1
    const int lane = tid & 63;
    const int lc   = (lane < HID) ? lane : (HID - 1);

    __shared__ __align__(16) float    xs[TSTEPS + 4];
    __shared__ __align__(16) _Float16 hbuf[80];   // [0..55] h+pad, [64..77] scratch
    __shared__ __align__(16) float    exch[256];  // [wv][j][lane]

    // Stage x (coalesced float4 loads, 128 threads).
    const float4* xb4 = (const float4*)(x + (size_t)b * TSTEPS);
    float4* xs4 = (float4*)xs;
    #pragma unroll
    for (int i = tid; i < TSTEPS / 4; i += 128) xs4[i] = xb4[i];
    if (tid == 0) xs[TSTEPS] = 0.0f;
    for (int i = tid; i < 80; i += 128) hbuf[i] = (_Float16)0.0f;

    // Gate columns: wave0 -> A=i (col lc), B=f (50+lc); wave1 -> A=g (100+lc), B=o (150+lc).
    const int   colA = (wv == 0) ? lc : (2 * HID + lc);
    const int   colB = (wv == 0) ? (HID + lc) : (3 * HID + lc);
    const float scA  = (wv == 0) ? -LOG2E : (2.0f * LOG2E);  // sigmoid: exp2(-Lz); tanh: exp2(+2Lz)
    const float scB  = -LOG2E;                               // f and o are sigmoids
    const float mA   = (wv == 0) ? 1.0f : -2.0f;             // act = fma(mA, s, aA)
    const float aA   = (wv == 0) ? 0.0f : 1.0f;

    // Recurrent weights for my 2 gates, packed along k as half2 (25 pairs).
    v2h wA[25], wB[25];
    #pragma unroll
    for (int p = 0; p < 25; ++p) {
        const float* r0 = Wh + (2 * p) * FOURH;
        const float* r1 = Wh + (2 * p + 1) * FOURH;
        wA[p] = v2h{(_Float16)(scA * r0[colA]), (_Float16)(scA * r1[colA])};
        wB[p] = v2h{(_Float16)(scB * r0[colB]), (_Float16)(scB * r1[colB])};
    }
    const float wxA = scA * Wx[colA], bsA = scA * bias[colA];
    const float wxB = scB * Wx[colB], bsB = scB * bias[colB];

    // Branchless h-write slot (wave0 only): real -> [0..49], dups -> [64..77].
    const int widx = (lane < HID) ? lane : (lane + 14);

    float c = 0.0f;
    float h = 0.0f;
    __syncthreads();   // staging visible

    const uint4* hb4 = (const uint4*)hbuf;
    float* exch_w = exch + wv * 128;          // my write area
    const float* exch_r = exch + (wv ^ 1) * 128;  // partner area

    float xt = xs[0];

    for (int t = 0; t < TSTEPS; ++t) {
        const float xt_next = xs[t + 1];

        // Packed h pairs (uniform-address broadcast reads, no repack).
        const uint4 q0 = hb4[0], q1 = hb4[1], q2 = hb4[2], q3 = hb4[3];
        const uint4 q4 = hb4[4], q5 = hb4[5], q6 = hb4[6];
        unsigned int hr[28] = {q0.x, q0.y, q0.z, q0.w, q1.x, q1.y, q1.z, q1.w,
                               q2.x, q2.y, q2.z, q2.w, q3.x, q3.y, q3.z, q3.w,
                               q4.x, q4.y, q4.z, q4.w, q5.x, q5.y, q5.z, q5.w,
                               q6.x, q6.y, q6.z, q6.w};

        // 4 independent dot2 chains (2 per gate), 50 dots total.
        float aA0 = 0.f, aA1 = 0.f, aB0 = 0.f, aB1 = 0.f;
        #pragma unroll
        for (int j = 0; j < 12; ++j) {
            const v2h h0 = bc_v2h(hr[2 * j]);
            const v2h h1 = bc_v2h(hr[2 * j + 1]);
            aA0 = __builtin_amdgcn_fdot2(wA[2 * j],     h0, aA0, false);
            aB0 = __builtin_amdgcn_fdot2(wB[2 * j],     h0, aB0, false);
            aA1 = __builtin_amdgcn_fdot2(wA[2 * j + 1], h1, aA1, false);
            aB1 = __builtin_amdgcn_fdot2(wB[2 * j + 1], h1, aB1, false);
        }
        {   // pair 24 (h48,h49)
            const v2h hp = bc_v2h(hr[24]);
            aA0 = __builtin_amdgcn_fdot2(wA[24], hp, aA0, false);
            aB0 = __builtin_amdgcn_fdot2(wB[24], hp, aB0, false);
        }

        const float zA = fmaf(xt, wxA, bsA) + (aA0 + aA1);
        const float zB = fmaf(xt, wxB, bsB) + (aB0 + aB1);

        const float sA   = frcp(1.0f + fexp2(zA));
        const float actA = fmaf(mA, sA, aA);          // wave0: ig ; wave1: gg
        const float actB = frcp(1.0f + fexp2(zB));    // wave0: fg ; wave1: og

        exch_w[lane]      = actA;
        exch_w[64 + lane] = actB;
        __syncthreads();
        const float pA = exch_r[lane];        // partner actA
        const float pB = exch_r[64 + lane];   // partner actB

        // ig*gg == actA*pA on BOTH waves (commutative) -> no select needed.
        const float prod = actA * pA;
        const float fg   = (wv == 0) ? actB : pB;
        const float og   = (wv == 0) ? pB   : actB;

        c = fmaf(fg, c, prod);
        const float tc = fmaf(-2.0f, frcp(1.0f + fexp2((2.0f * LOG2E) * c)), 1.0f);
        h = og * tc;

        if (wv == 0) hbuf[widx] = (_Float16)h;   // visible after barrier below
        __syncthreads();
        xt = xt_next;
    }

    // out[b] = h_T . Wd + bd  (both waves hold identical h; wave0 reduces)
    if (wv == 0) {
        float v = (lane < HID) ? h * Wd[lane] : 0.0f;
        #pragma unroll
        for (int off = 32; off > 0; off >>= 1) v += __shfl_down(v, off);
        if (lane == 0) out[b] = v + bd[0];
    }
}

extern "C" void kernel_launch(void* const* d_in, const int* in_sizes, int n_in,
                              void* d_out, int out_size, void* d_ws, size_t ws_size,
                              hipStream_t stream) {
    const float* x    = (const float*)d_in[0];  // [1024, 2048, 1]
    const float* Wx   = (const float*)d_in[1];  // [1, 200]
    const float* Wh   = (const float*)d_in[2];  // [50, 200]
    const float* bias = (const float*)d_in[3];  // [200]
    const float* Wd   = (const float*)d_in[4];  // [50, 1]
    const float* bd   = (const float*)d_in[5];  // [1]
    float* out = (float*)d_out;                 // [1024, 1]

    lstm_2wave_kernel<<<dim3(NBATCH), dim3(128), 0, stream>>>(
        x, Wx, Wh, bias, Wd, bd, out);
}